// Round 11
// baseline (3458.396 us; speedup 1.0000x reference)
//
#include <hip/hip_runtime.h>

typedef unsigned short ushort_t;
typedef __attribute__((ext_vector_type(8))) short bf16x8;
typedef __attribute__((ext_vector_type(4))) float f32x4;

#define FIN 6
#define CAP2 9216      // per-512-node-bucket edge capacity (mean 8192, +11 sigma)
#define EPB 18         // CAP2 / 512 staged edges per thread
#define LNCAP 384      // max nodes/graph staged in LDS for LN

__device__ __forceinline__ float blo(unsigned u) { return __uint_as_float(u << 16); }
__device__ __forceinline__ float bhi(unsigned u) { return __uint_as_float(u & 0xffff0000u); }
__device__ __forceinline__ ushort_t f2b(float f) {
  unsigned u = __float_as_uint(f);
  unsigned r = (u + 0x7fffu + ((u >> 16) & 1u)) >> 16;
  return (ushort_t)r;
}
__device__ __forceinline__ unsigned pk2(float lo, float hi) {
  return ((unsigned)f2b(hi) << 16) | (unsigned)f2b(lo);
}
union U4F { uint4 u; bf16x8 v; };
__device__ __forceinline__ bf16x8 asfrag(uint4 u) { U4F x; x.u = u; return x.v; }

// XCD-aware block swizzle: grid B (multiple of 8). XCDs 0-3 -> first half of
// buckets (graph1), XCDs 4-7 -> second half (graph2).
__device__ __forceinline__ int xcd_swz(int b, int B) {
  int xcd = b & 7, sub = b >> 3;
  int bpx = B >> 3;
  return (xcd >> 2) * (B >> 1) + (xcd & 3) * bpx + sub;
}

// ================= bucketed edge build (512-node buckets, both graphs) =================
#define EPT 16
#define TILE 8192      // 512 threads * EPT

// wpack (blocks 0-5) + binit (block 6)
__global__ __launch_bounds__(256) void k_wpack(const float* __restrict__ W2,
    const float* __restrict__ W3, const float* __restrict__ W4, uint4* __restrict__ wfrag,
    int* __restrict__ ecur, int nbuk) {
  if (blockIdx.x == 6) {
    for (int j = threadIdx.x; j < 1024; j += 256) ecur[j] = j * CAP2;
    return;
  }
  int idx = blockIdx.x * 256 + threadIdx.x;
  if (idx >= 3 * 512) return;
  int widx = idx >> 9, rem = idx & 511;
  int mt = rem >> 7, kh = (rem >> 6) & 1, l = rem & 63;
  int g = l >> 4, c = l & 15;
  const float* W = (widx == 0) ? W2 : (widx == 1) ? W3 : W4;
  int k0 = kh * 32 + g * 8;
  int col = mt * 16 + c;
  uint4 v;
  v.x = pk2(W[(k0 + 0) * 64 + col], W[(k0 + 1) * 64 + col]);
  v.y = pk2(W[(k0 + 2) * 64 + col], W[(k0 + 3) * 64 + col]);
  v.z = pk2(W[(k0 + 4) * 64 + col], W[(k0 + 5) * 64 + col]);
  v.w = pk2(W[(k0 + 6) * 64 + col], W[(k0 + 7) * 64 + col]);
  wfrag[idx] = v;
}

// ebuf word: dstLocal(9) << 19 | src(19).  bucket = dstGlobal >> 9.
__global__ __launch_bounds__(512) void k_bscatter(
    const int* __restrict__ src1, const int* __restrict__ dst1, int E1,
    const int* __restrict__ src2, const int* __restrict__ dst2, int E2,
    int* __restrict__ ecur, unsigned* __restrict__ ebuf, int N, int nbuk) {
  __shared__ int cnt[1024];
  __shared__ int gbase[1024];
  int t = threadIdx.x;
  cnt[t] = 0; cnt[t + 512] = 0;
  __syncthreads();
  int tile = blockIdx.x;
  int T1 = (E1 + TILE - 1) / TILE;
  const int* srcp; const int* dstp; int Elim, ofs, base;
  if (tile < T1) { srcp = src1; dstp = dst1; Elim = E1; ofs = 0; base = tile * TILE; }
  else { srcp = src2; dstp = dst2; Elim = E2; ofs = N; base = (tile - T1) * TILE; }
  unsigned pk[EPT];   // bucket(10) | rank<<10
  unsigned pv[EPT];   // dstLocal(9)<<19 | src(19)
  #pragma unroll
  for (int k = 0; k < EPT; ++k) {
    int e = base + k * 512 + t;
    if (e < Elim) {
      int d = dstp[e] + ofs;
      int b = d >> 9;
      int r = atomicAdd(&cnt[b], 1);
      pk[k] = (unsigned)b | ((unsigned)r << 10);
      pv[k] = ((unsigned)(d & 511) << 19) | (unsigned)(srcp[e] + ofs);
    } else {
      pk[k] = 0xFFFFFFFFu;
    }
  }
  __syncthreads();
  if (cnt[t] > 0) gbase[t] = atomicAdd(&ecur[t], cnt[t]);
  if (cnt[t + 512] > 0) gbase[t + 512] = atomicAdd(&ecur[t + 512], cnt[t + 512]);
  __syncthreads();
  #pragma unroll
  for (int k = 0; k < EPT; ++k) {
    if (pk[k] != 0xFFFFFFFFu) {
      int b = pk[k] & 1023;
      int r = pk[k] >> 10;
      ebuf[gbase[b] + r] = pv[k];
    }
  }
}

// ---------------- prep: xpack both graphs + combined graph bounds ----------------
__global__ void k_prep(const float* __restrict__ x1, const float* __restrict__ x2,
                       const int* __restrict__ batch1, const int* __restrict__ batch2,
                       unsigned* __restrict__ xb, int* __restrict__ gstart,
                       int N, int G) {
  int N2 = 2 * N, G2 = 2 * G;
  int tt = blockIdx.x * 256 + threadIdx.x;
  if (tt < N2 * 4) {
    int i = tt >> 2, k = tt & 3;
    unsigned v = 0;
    if (k < 3) {
      const float* xp = (i < N) ? (x1 + (size_t)i * 6) : (x2 + (size_t)(i - N) * 6);
      float2 f = *(const float2*)(xp + k * 2);
      v = pk2(f.x, f.y);
    }
    xb[tt] = v;
  }
  if (tt < N2) {
    int i = tt;
    int b = (i < N) ? batch1[i] : (batch2[i - N] + G);
    if (i == 0) { for (int g = 0; g <= b; ++g) gstart[g] = 0; }
    else {
      int pb = (i - 1 < N) ? batch1[i - 1] : (batch2[i - 1 - N] + G);
      for (int g = pb + 1; g <= b; ++g) gstart[g] = i;
    }
    if (i == N2 - 1) { for (int g = b + 1; g <= G2; ++g) gstart[g] = N2; }
  }
}

// ---------------- GIN1 edge-centric: LDS accum x-gather + MLP(6->64) + MFMA(64->64) ----------------
__global__ __launch_bounds__(512) void k_gin1e(const uint4* __restrict__ xb4,
    const int* __restrict__ ecur, const unsigned* __restrict__ ebuf,
    const float* __restrict__ W1, const float* __restrict__ b1,
    const uint4* __restrict__ wf2, const float* __restrict__ b2,
    ushort_t* __restrict__ hr, int nbuk, int n) {
  __shared__ float acc6[512][6];
  __shared__ __align__(16) ushort_t t1w[8][16][72];
  int t = threadIdx.x;
  int blk = xcd_swz(blockIdx.x, gridDim.x);
  if (blk >= nbuk) return;
  for (int j = t; j < 512 * 6; j += 512) ((float*)acc6)[j] = 0.f;
  int e0 = blk * CAP2, e1 = ecur[blk];
  unsigned ev[EPB]; int kc = 0;
  #pragma unroll
  for (int k = 0; k < EPB; ++k) {
    int e = e0 + k * 512 + t;
    if (e < e1) ev[kc++] = ebuf[e];
  }
  __syncthreads();
  for (int k = 0; k < kc; ++k) {
    unsigned e = ev[k];
    int src = e & 0x7FFFF, dl = e >> 19;
    uint4 u = xb4[src];
    atomicAdd(&acc6[dl][0], blo(u.x)); atomicAdd(&acc6[dl][1], bhi(u.x));
    atomicAdd(&acc6[dl][2], blo(u.y)); atomicAdd(&acc6[dl][3], bhi(u.y));
    atomicAdd(&acc6[dl][4], blo(u.z)); atomicAdd(&acc6[dl][5], bhi(u.z));
  }
  __syncthreads();
  int i = blk * 512 + t;
  if (i < n) {
    uint4 u = xb4[i];
    acc6[t][0] += blo(u.x); acc6[t][1] += bhi(u.x); acc6[t][2] += blo(u.y);
    acc6[t][3] += bhi(u.y); acc6[t][4] += blo(u.z); acc6[t][5] += bhi(u.z);
  }
  __syncthreads();
  int w = t >> 6, lane = t & 63;
  int g = lane >> 4, c = lane & 15;
  float w1r[FIN];
  #pragma unroll
  for (int k = 0; k < FIN; ++k) w1r[k] = W1[k * 64 + lane];
  float bb1 = b1[lane];
  bf16x8 af[4][2];
  #pragma unroll
  for (int mt = 0; mt < 4; ++mt)
    #pragma unroll
    for (int kh = 0; kh < 2; ++kh) af[mt][kh] = asfrag(wf2[(mt * 2 + kh) * 64 + lane]);
  float bs[4][4];
  #pragma unroll
  for (int mt = 0; mt < 4; ++mt)
    #pragma unroll
    for (int r = 0; r < 4; ++r) bs[mt][r] = b2[mt * 16 + 4 * g + r];

  for (int tt = 0; tt < 4; ++tt) {
    int nb = w * 64 + tt * 16;
    for (int nd2 = 0; nd2 < 16; ++nd2) {
      int nl = nb + nd2;
      float h = bb1;
      #pragma unroll
      for (int k = 0; k < FIN; ++k) h = fmaf(acc6[nl][k], w1r[k], h);
      t1w[w][nd2][lane] = f2b(fmaxf(h, 0.f));
    }
    // same-wave LDS ops are in-order; wave-private slice
    bf16x8 bf0 = asfrag(*(const uint4*)&t1w[w][c][8 * g]);
    bf16x8 bf1 = asfrag(*(const uint4*)&t1w[w][c][8 * g + 32]);
    f32x4 a4[4];
    #pragma unroll
    for (int mt = 0; mt < 4; ++mt) {
      a4[mt] = (f32x4){bs[mt][0], bs[mt][1], bs[mt][2], bs[mt][3]};
      a4[mt] = __builtin_amdgcn_mfma_f32_16x16x32_bf16(af[mt][0], bf0, a4[mt], 0, 0, 0);
      a4[mt] = __builtin_amdgcn_mfma_f32_16x16x32_bf16(af[mt][1], bf1, a4[mt], 0, 0, 0);
    }
    #pragma unroll
    for (int mt = 0; mt < 4; ++mt) {
      uint2 pv;
      pv.x = pk2(a4[mt][0], a4[mt][1]);
      pv.y = pk2(a4[mt][2], a4[mt][3]);
      *(uint2*)&t1w[w][c][mt * 16 + 4 * g] = pv;
    }
    int n2 = lane >> 2, ch = (lane & 3) * 16;
    uint4 s0 = *(const uint4*)&t1w[w][n2][ch];
    uint4 s1 = *(const uint4*)&t1w[w][n2][ch + 8];
    int orow = blk * 512 + nb + n2;
    if (orow < n) {
      uint4* op = (uint4*)(hr + (size_t)orow * 64);
      op[(lane & 3) * 2] = s0;
      op[(lane & 3) * 2 + 1] = s1;
    }
  }
}

// ---------------- agg edge-centric: src-sliced passes + LDS fp32 accum ----------------
#define ACCW 65    // padded row stride (floats) to spread LDS banks
__global__ __launch_bounds__(512) void k_agge(const ushort_t* __restrict__ hr,
    const int* __restrict__ ecur, const unsigned* __restrict__ ebuf,
    ushort_t* __restrict__ aggb, int nbuk, int n) {
  __shared__ float acc[512 * ACCW];
  __shared__ unsigned q[1024];
  __shared__ int qcnt;
  int t = threadIdx.x;
  int blk = xcd_swz(blockIdx.x, gridDim.x);
  if (blk >= nbuk) return;
  for (int j = t; j < 512 * ACCW; j += 512) acc[j] = 0.f;
  int e0 = blk * CAP2, e1 = ecur[blk];
  unsigned ev[EPB]; int kc = 0;
  #pragma unroll
  for (int k = 0; k < EPB; ++k) {
    int e = e0 + k * 512 + t;
    if (e < e1) ev[kc++] = ebuf[e];
  }
  int grp = t >> 3, sl = t & 7, lane = t & 63;
  unsigned long long lmask = (1ull << lane) - 1ull;
  const uint4* hb4 = (const uint4*)hr;
  __syncthreads();
  for (int s = 0; s < 32; ++s) {
    if (t == 0) qcnt = 0;
    __syncthreads();
    #pragma unroll
    for (int k = 0; k < EPB; ++k) {
      unsigned e = (k < kc) ? ev[k] : 0xFFFFFFFFu;
      bool m = (k < kc) && (((e >> 14) & 31u) == (unsigned)s);
      unsigned long long msk = __ballot(m);
      if (m) {
        int leader = __ffsll((long long)msk) - 1;
        int rank = __popcll(msk & lmask);
        int base = 0;
        if (lane == leader) base = atomicAdd(&qcnt, __popcll(msk));
        base = __shfl(base, leader);
        q[base + rank] = e;
      }
    }
    __syncthreads();
    int tot = qcnt;
    for (int p = grp; p < tot; p += 128) {
      unsigned ea = q[p];
      bool h2 = (p + 64) < tot;
      unsigned eb = h2 ? q[p + 64] : 0;
      int sa = ea & 0x7FFFF, da = ea >> 19;
      int sb = eb & 0x7FFFF, db = eb >> 19;
      uint4 ua = hb4[(size_t)sa * 8 + sl];
      uint4 ub;
      if (h2) ub = hb4[(size_t)sb * 8 + sl];
      float* pa = &acc[da * ACCW + sl * 8];
      atomicAdd(pa + 0, blo(ua.x)); atomicAdd(pa + 1, bhi(ua.x));
      atomicAdd(pa + 2, blo(ua.y)); atomicAdd(pa + 3, bhi(ua.y));
      atomicAdd(pa + 4, blo(ua.z)); atomicAdd(pa + 5, bhi(ua.z));
      atomicAdd(pa + 6, blo(ua.w)); atomicAdd(pa + 7, bhi(ua.w));
      if (h2) {
        float* pb = &acc[db * ACCW + sl * 8];
        atomicAdd(pb + 0, blo(ub.x)); atomicAdd(pb + 1, bhi(ub.x));
        atomicAdd(pb + 2, blo(ub.y)); atomicAdd(pb + 3, bhi(ub.y));
        atomicAdd(pb + 4, blo(ub.z)); atomicAdd(pb + 5, bhi(ub.z));
        atomicAdd(pb + 6, blo(ub.w)); atomicAdd(pb + 7, bhi(ub.w));
      }
    }
    __syncthreads();
  }
  // flush: add bf16 self row, pack bf16, store
  for (int r = 0; r < 8; ++r) {
    int nl = r * 64 + grp;
    int i = blk * 512 + nl;
    if (i < n) {
      uint4 us = hb4[(size_t)i * 8 + sl];
      const float* a = &acc[nl * ACCW + sl * 8];
      float a0 = a[0] + blo(us.x), a1 = a[1] + bhi(us.x);
      float a2 = a[2] + blo(us.y), a3 = a[3] + bhi(us.y);
      float a4 = a[4] + blo(us.z), a5 = a[5] + bhi(us.z);
      float a6 = a[6] + blo(us.w), a7 = a[7] + bhi(us.w);
      uint4 o;
      o.x = pk2(a0, a1); o.y = pk2(a2, a3); o.z = pk2(a4, a5); o.w = pk2(a6, a7);
      ((uint4*)aggb)[(size_t)i * 8 + sl] = o;
    }
  }
}

// ---------------- k_mlp2_mfma (unchanged) ----------------
__global__ __launch_bounds__(256) void k_mlp2_mfma(const ushort_t* __restrict__ aggb,
    const uint4* __restrict__ wf3, const float* __restrict__ b3,
    const uint4* __restrict__ wf4, const float* __restrict__ b4,
    ushort_t* __restrict__ zb, int n) {
  __shared__ __align__(16) ushort_t lds[4][16][72];
  int t = threadIdx.x, w = t >> 6, l = t & 63;
  int g = l >> 4, c = l & 15;
  bf16x8 a3[4][2], a4[4][2];
  #pragma unroll
  for (int mt = 0; mt < 4; ++mt)
    #pragma unroll
    for (int kh = 0; kh < 2; ++kh) {
      a3[mt][kh] = asfrag(wf3[(mt * 2 + kh) * 64 + l]);
      a4[mt][kh] = asfrag(wf4[(mt * 2 + kh) * 64 + l]);
    }
  float bs3[4][4], bs4[4][4];
  #pragma unroll
  for (int mt = 0; mt < 4; ++mt)
    #pragma unroll
    for (int r = 0; r < 4; ++r) {
      bs3[mt][r] = b3[mt * 16 + 4 * g + r];
      bs4[mt][r] = b4[mt * 16 + 4 * g + r];
    }
  int ntile = (n + 15) >> 4;
  for (int tau = blockIdx.x * 4 + w; tau < ntile; tau += gridDim.x * 4) {
    int nb = tau << 4;
    int row = nb + c; if (row >= n) row = n - 1;
    const uint4* rp = (const uint4*)(aggb + (size_t)row * 64);
    bf16x8 bf0 = asfrag(rp[g]);
    bf16x8 bf1 = asfrag(rp[g + 4]);
    f32x4 acc[4];
    #pragma unroll
    for (int mt = 0; mt < 4; ++mt) {
      acc[mt] = (f32x4){bs3[mt][0], bs3[mt][1], bs3[mt][2], bs3[mt][3]};
      acc[mt] = __builtin_amdgcn_mfma_f32_16x16x32_bf16(a3[mt][0], bf0, acc[mt], 0, 0, 0);
      acc[mt] = __builtin_amdgcn_mfma_f32_16x16x32_bf16(a3[mt][1], bf1, acc[mt], 0, 0, 0);
    }
    #pragma unroll
    for (int mt = 0; mt < 4; ++mt) {
      uint2 pv;
      pv.x = pk2(fmaxf(acc[mt][0], 0.f), fmaxf(acc[mt][1], 0.f));
      pv.y = pk2(fmaxf(acc[mt][2], 0.f), fmaxf(acc[mt][3], 0.f));
      *(uint2*)&lds[w][c][mt * 16 + 4 * g] = pv;
    }
    bf16x8 h0 = asfrag(*(const uint4*)&lds[w][c][8 * g]);
    bf16x8 h1 = asfrag(*(const uint4*)&lds[w][c][8 * g + 32]);
    f32x4 ac2[4];
    #pragma unroll
    for (int mt = 0; mt < 4; ++mt) {
      ac2[mt] = (f32x4){bs4[mt][0], bs4[mt][1], bs4[mt][2], bs4[mt][3]};
      ac2[mt] = __builtin_amdgcn_mfma_f32_16x16x32_bf16(a4[mt][0], h0, ac2[mt], 0, 0, 0);
      ac2[mt] = __builtin_amdgcn_mfma_f32_16x16x32_bf16(a4[mt][1], h1, ac2[mt], 0, 0, 0);
    }
    #pragma unroll
    for (int mt = 0; mt < 4; ++mt) {
      uint2 pv;
      pv.x = pk2(ac2[mt][0], ac2[mt][1]);
      pv.y = pk2(ac2[mt][2], ac2[mt][3]);
      *(uint2*)&lds[w][c][mt * 16 + 4 * g] = pv;
    }
    int n2 = l >> 2, ch = (l & 3) * 16;
    uint4 s0 = *(const uint4*)&lds[w][n2][ch];
    uint4 s1 = *(const uint4*)&lds[w][n2][ch + 8];
    int orow = nb + n2;
    if (orow < n) {
      uint4* op = (uint4*)(zb + (size_t)orow * 64);
      op[(l & 3) * 2] = s0;
      op[(l & 3) * 2 + 1] = s1;
    }
  }
}

// ---------------- LN1 fused: stats + apply + relu (block per graph, in-place) ----------------
__global__ __launch_bounds__(256) void k_ln1(ushort_t* __restrict__ hr,
    const int* __restrict__ gstart, const float* __restrict__ w, const float* __restrict__ bb) {
  __shared__ uint4 st[LNCAP * 8];
  __shared__ float l1[256], l2[256];
  __shared__ float mm[2];
  int g = blockIdx.x, t = threadIdx.x;
  int s0 = gstart[g], s1 = gstart[g + 1], cnt = s1 - s0;
  uint4* src = (uint4*)hr + (size_t)s0 * 8;
  int nch = cnt * 8;
  bool fit = cnt <= LNCAP;
  float s = 0.f, ss = 0.f;
  for (int j = t; j < nch; j += 256) {
    uint4 u = src[j];
    if (fit) st[j] = u;
    float v0 = blo(u.x), v1 = bhi(u.x), v2 = blo(u.y), v3 = bhi(u.y);
    float v4 = blo(u.z), v5 = bhi(u.z), v6 = blo(u.w), v7 = bhi(u.w);
    s += ((v0 + v1) + (v2 + v3)) + ((v4 + v5) + (v6 + v7));
    ss += ((v0 * v0 + v1 * v1) + (v2 * v2 + v3 * v3)) + ((v4 * v4 + v5 * v5) + (v6 * v6 + v7 * v7));
  }
  l1[t] = s; l2[t] = ss;
  __syncthreads();
  for (int o = 128; o > 0; o >>= 1) {
    if (t < o) { l1[t] += l1[t + o]; l2[t] += l2[t + o]; }
    __syncthreads();
  }
  if (t == 0) {
    float cf = (float)cnt;
    float norm = fmaxf(cf, 1.f) * 64.f;
    float mean = l1[0] / norm;
    float var = fmaxf(l2[0] / norm - mean * mean, 0.f);
    mm[0] = mean; mm[1] = rsqrtf(var + 1e-5f);
  }
  __syncthreads();
  float mean = mm[0], inv = mm[1];
  for (int j = t; j < nch; j += 256) {
    uint4 u = fit ? st[j] : src[j];
    int q = j & 7;
    float4 w0 = *(const float4*)(w + q * 8);
    float4 w1 = *(const float4*)(w + q * 8 + 4);
    float4 c0 = *(const float4*)(bb + q * 8);
    float4 c1 = *(const float4*)(bb + q * 8 + 4);
    uint4 o;
    o.x = pk2(fmaxf((blo(u.x) - mean) * inv * w0.x + c0.x, 0.f),
              fmaxf((bhi(u.x) - mean) * inv * w0.y + c0.y, 0.f));
    o.y = pk2(fmaxf((blo(u.y) - mean) * inv * w0.z + c0.z, 0.f),
              fmaxf((bhi(u.y) - mean) * inv * w0.w + c0.w, 0.f));
    o.z = pk2(fmaxf((blo(u.z) - mean) * inv * w1.x + c1.x, 0.f),
              fmaxf((bhi(u.z) - mean) * inv * w1.y + c1.y, 0.f));
    o.w = pk2(fmaxf((blo(u.w) - mean) * inv * w1.z + c1.z, 0.f),
              fmaxf((bhi(u.w) - mean) * inv * w1.w + c1.w, 0.f));
    src[j] = o;
  }
}

// ---------------- LN2 + pool fused ----------------
__global__ __launch_bounds__(256) void k_ln2pool(const ushort_t* __restrict__ zb,
    const int* __restrict__ gstart, const float* __restrict__ w, const float* __restrict__ bb,
    float* __restrict__ emb) {
  __shared__ unsigned st[LNCAP * 32];
  __shared__ float l1[256], l2[256];
  __shared__ float mm[2];
  int g = blockIdx.x, t = threadIdx.x;
  int s0 = gstart[g], s1 = gstart[g + 1], cnt = s1 - s0;
  const unsigned* src = (const unsigned*)zb + (size_t)s0 * 32;
  int nu = cnt * 32;
  bool fit = cnt <= LNCAP;
  float s = 0.f, ss = 0.f;
  for (int j = t; j < nu; j += 256) {
    unsigned u = src[j];
    if (fit) st[j] = u;
    float v0 = blo(u), v1 = bhi(u);
    s += v0 + v1;
    ss += v0 * v0 + v1 * v1;
  }
  l1[t] = s; l2[t] = ss;
  __syncthreads();
  for (int o = 128; o > 0; o >>= 1) {
    if (t < o) { l1[t] += l1[t + o]; l2[t] += l2[t + o]; }
    __syncthreads();
  }
  if (t == 0) {
    float cf = (float)cnt;
    float norm = fmaxf(cf, 1.f) * 64.f;
    float mean = l1[0] / norm;
    float var = fmaxf(l2[0] / norm - mean * mean, 0.f);
    mm[0] = mean; mm[1] = rsqrtf(var + 1e-5f);
  }
  __syncthreads();
  float mean = mm[0], inv = mm[1];
  int c2 = t & 31, sub = t >> 5;
  float w0 = w[c2 * 2], w1 = w[c2 * 2 + 1], b0 = bb[c2 * 2], b1v = bb[c2 * 2 + 1];
  float acc0 = 0.f, acc1 = 0.f;
  for (int i = sub; i < cnt; i += 8) {
    unsigned u = fit ? st[i * 32 + c2] : src[(size_t)i * 32 + c2];
    acc0 += fmaxf((blo(u) - mean) * inv * w0 + b0, 0.f);
    acc1 += fmaxf((bhi(u) - mean) * inv * w1 + b1v, 0.f);
  }
  __syncthreads();
  l1[t] = acc0; l2[t] = acc1;
  __syncthreads();
  if (sub == 0) {
    float t0 = 0.f, t1v = 0.f;
    #pragma unroll
    for (int sx = 0; sx < 8; ++sx) { t0 += l1[sx * 32 + c2]; t1v += l2[sx * 32 + c2]; }
    float cf = fmaxf((float)cnt, 1.f);
    emb[g * 64 + c2 * 2]     = t0 + t0 / cf;
    emb[g * 64 + c2 * 2 + 1] = t1v + t1v / cf;
  }
}

// ---------------- head MLP ----------------
__global__ __launch_bounds__(128) void k_head(const float* __restrict__ emb1,
    const float* __restrict__ emb2, const float* __restrict__ d1, const float* __restrict__ d2,
    const float* __restrict__ Wf1, const float* __restrict__ bf1,
    const float* __restrict__ Wf2, const float* __restrict__ bf2,
    const float* __restrict__ Wo, const float* __restrict__ bo, float* __restrict__ out) {
  int g = blockIdx.x, t = threadIdx.x;
  __shared__ float v[138], h1s[128], h2s[64];
  if (t < 64) v[t] = emb1[g * 64 + t];
  else v[t] = emb2[g * 64 + (t - 64)];
  if (t < 5) v[128 + t] = d1[g * 5 + t];
  else if (t < 10) v[133 + (t - 5)] = d2[g * 5 + (t - 5)];
  __syncthreads();
  float a = bf1[t];
  for (int k = 0; k < 138; ++k) a = fmaf(v[k], Wf1[k * 128 + t], a);
  h1s[t] = fmaxf(a, 0.f);
  __syncthreads();
  if (t < 64) {
    float a2 = bf2[t];
    #pragma unroll 8
    for (int k = 0; k < 128; ++k) a2 = fmaf(h1s[k], Wf2[k * 64 + t], a2);
    h2s[t] = fmaxf(a2, 0.f);
  }
  __syncthreads();
  if (t == 0) {
    float s = bo[0];
    for (int k = 0; k < 64; ++k) s += h2s[k] * Wo[k];
    out[g] = s;
  }
}

extern "C" void kernel_launch(void* const* d_in, const int* in_sizes, int n_in,
                              void* d_out, int out_size, void* d_ws, size_t ws_size,
                              hipStream_t stream) {
  const float* x1     = (const float*)d_in[0];
  const int*   ei1    = (const int*)d_in[1];
  const int*   batch1 = (const int*)d_in[2];
  const float* x2     = (const float*)d_in[3];
  const int*   ei2    = (const int*)d_in[4];
  const int*   batch2 = (const int*)d_in[5];
  const float* d1     = (const float*)d_in[6];
  const float* d2     = (const float*)d_in[7];
  const float* W1  = (const float*)d_in[8],  *b1  = (const float*)d_in[9];
  const float* W2  = (const float*)d_in[10], *b2  = (const float*)d_in[11];
  const float* ln1w = (const float*)d_in[12], *ln1b = (const float*)d_in[13];
  const float* W3  = (const float*)d_in[14], *b3  = (const float*)d_in[15];
  const float* W4  = (const float*)d_in[16], *b4  = (const float*)d_in[17];
  const float* ln2w = (const float*)d_in[18], *ln2b = (const float*)d_in[19];
  const float* Wf1 = (const float*)d_in[20], *bf1 = (const float*)d_in[21];
  const float* Wf2 = (const float*)d_in[22], *bf2 = (const float*)d_in[23];
  const float* Wo  = (const float*)d_in[24], *bo  = (const float*)d_in[25];
  float* out = (float*)d_out;

  const int N = in_sizes[0] / FIN;
  const int G = in_sizes[6] / 5;
  const int E1 = in_sizes[1] / 2;
  const int E2 = in_sizes[4] / 2;
  const int N2 = 2 * N;
  const int NBUK2 = (N2 + 511) >> 9;   // 512-node buckets, <= 1024 (2N <= 524288)

  char* p = (char*)d_ws;
  auto alloc = [&](size_t bytes) { void* r = p; p += (bytes + 255) & ~(size_t)255; return r; };
  int*      ecur   = (int*)alloc(1024 * 4);
  int*      gstart = (int*)alloc((size_t)(2 * G + 1) * 4);
  uint4*    wfrag  = (uint4*)alloc(3 * 512 * 16);
  unsigned* ebuf   = (unsigned*)alloc((size_t)1024 * CAP2 * 4);  // 37.7 MB; dead after agge
  ushort_t* bufA   = (ushort_t*)alloc((size_t)N2 * 64 * 2);      // hr -> (LN in-place) -> zb
  ushort_t* aggb   = (ushort_t*)alloc((size_t)N2 * 64 * 2);      // xb aliases its head

  unsigned* xb  = (unsigned*)aggb;       // xb dead before agge writes aggb
  ushort_t* hr  = bufA;
  ushort_t* zb  = bufA;                  // hr dead after agge
  float*    emb = (float*)ebuf;          // ebuf dead after agge

  const uint4* wf2 = wfrag;
  const uint4* wf3 = wfrag + 512;
  const uint4* wf4 = wfrag + 1024;

  const int SCAT    = (E1 + TILE - 1) / TILE + (E2 + TILE - 1) / TILE;
  const int GRID_B  = (NBUK2 + 7) & ~7;     // xcd-swizzled bucket grids
  const int GRID_P  = (N2 * 4 + 255) / 256;

  k_wpack<<<7, 256, 0, stream>>>(W2, W3, W4, wfrag, ecur, NBUK2);
  k_bscatter<<<SCAT, 512, 0, stream>>>(ei1, ei1 + E1, E1, ei2, ei2 + E2, E2, ecur, ebuf, N, NBUK2);
  k_prep<<<GRID_P, 256, 0, stream>>>(x1, x2, batch1, batch2, xb, gstart, N, G);

  k_gin1e<<<GRID_B, 512, 0, stream>>>((const uint4*)xb, ecur, ebuf, W1, b1, wf2, b2, hr, NBUK2, N2);
  k_ln1<<<2 * G, 256, 0, stream>>>(hr, gstart, ln1w, ln1b);
  k_agge<<<GRID_B, 512, 0, stream>>>(hr, ecur, ebuf, aggb, NBUK2, N2);
  k_mlp2_mfma<<<2048, 256, 0, stream>>>(aggb, wf3, b3, wf4, b4, zb, N2);
  k_ln2pool<<<2 * G, 256, 0, stream>>>(zb, gstart, ln2w, ln2b, emb);

  k_head<<<G, 128, 0, stream>>>(emb, emb + (size_t)G * 64, d1, d2, Wf1, bf1, Wf2, bf2, Wo, bo, out);
}

// Round 12
// 546.999 us; speedup vs baseline: 6.3225x; 6.3225x over previous
//
#include <hip/hip_runtime.h>

typedef unsigned short ushort_t;
typedef __attribute__((ext_vector_type(8))) short bf16x8;
typedef __attribute__((ext_vector_type(4))) float f32x4;

#define FIN 6
#define CAP 20480      // per-bucket edge capacity (mean 16384 at E=8M, 489 buckets)
#define LNCAP 384      // max nodes/graph staged in LDS

__device__ __forceinline__ float blo(unsigned u) { return __uint_as_float(u << 16); }
__device__ __forceinline__ float bhi(unsigned u) { return __uint_as_float(u & 0xffff0000u); }
__device__ __forceinline__ ushort_t f2b(float f) {
  unsigned u = __float_as_uint(f);
  unsigned r = (u + 0x7fffu + ((u >> 16) & 1u)) >> 16;
  return (ushort_t)r;
}
__device__ __forceinline__ unsigned pk2(float lo, float hi) {
  return ((unsigned)f2b(hi) << 16) | (unsigned)f2b(lo);
}
union U4F { uint4 u; bf16x8 v; };
__device__ __forceinline__ bf16x8 asfrag(uint4 u) { U4F x; x.u = u; return x.v; }

// XCD-aware block swizzle: grid B (multiple of 8). XCDs 0-3 -> first half of
// work (graph1), XCDs 4-7 -> second half (graph2). blockIdx%8 is the XCD.
__device__ __forceinline__ int xcd_swz(int b, int B) {
  int xcd = b & 7, sub = b >> 3;
  int bpx = B >> 3;
  return (xcd >> 2) * (B >> 1) + (xcd & 3) * bpx + sub;
}

// ================= bucketed CSR build (both graphs, node ids offset) =================
#define EPT 16
#define TILE 8192      // 512 threads * EPT

// blocks 0-5: wpack; block 6: binit; blocks 7+: xpack + graph bounds (prep)
__global__ __launch_bounds__(256) void k_wpack(const float* __restrict__ W2,
    const float* __restrict__ W3, const float* __restrict__ W4, uint4* __restrict__ wfrag,
    int* __restrict__ ecur, int* __restrict__ off, int nbuk, int N2, int Etot,
    const float* __restrict__ x1, const float* __restrict__ x2,
    const int* __restrict__ batch1, const int* __restrict__ batch2,
    unsigned* __restrict__ xb, int* __restrict__ gstart, int N, int G) {
  if (blockIdx.x >= 7) {
    int G2 = 2 * G;
    int tt = (blockIdx.x - 7) * 256 + threadIdx.x;
    if (tt < N2 * 4) {
      int i = tt >> 2, k = tt & 3;
      unsigned v = 0;
      if (k < 3) {
        const float* xp = (i < N) ? (x1 + (size_t)i * 6) : (x2 + (size_t)(i - N) * 6);
        float2 f = *(const float2*)(xp + k * 2);
        v = pk2(f.x, f.y);
      }
      xb[tt] = v;
    }
    if (tt < N2) {
      int i = tt;
      int b = (i < N) ? batch1[i] : (batch2[i - N] + G);
      if (i == 0) { for (int g = 0; g <= b; ++g) gstart[g] = 0; }
      else {
        int pb = (i - 1 < N) ? batch1[i - 1] : (batch2[i - 1 - N] + G);
        for (int g = pb + 1; g <= b; ++g) gstart[g] = i;
      }
      if (i == N2 - 1) { for (int g = b + 1; g <= G2; ++g) gstart[g] = N2; }
    }
    return;
  }
  if (blockIdx.x == 6) {
    int t = threadIdx.x;
    if (t < nbuk) ecur[t] = t * CAP;
    if (t + 256 < nbuk) ecur[t + 256] = (t + 256) * CAP;
    if (t == 0) off[N2] = Etot;
    return;
  }
  int idx = blockIdx.x * 256 + threadIdx.x;
  if (idx >= 3 * 512) return;
  int widx = idx >> 9, rem = idx & 511;
  int mt = rem >> 7, kh = (rem >> 6) & 1, l = rem & 63;
  int g = l >> 4, c = l & 15;
  const float* W = (widx == 0) ? W2 : (widx == 1) ? W3 : W4;
  int k0 = kh * 32 + g * 8;
  int col = mt * 16 + c;
  uint4 v;
  v.x = pk2(W[(k0 + 0) * 64 + col], W[(k0 + 1) * 64 + col]);
  v.y = pk2(W[(k0 + 2) * 64 + col], W[(k0 + 3) * 64 + col]);
  v.z = pk2(W[(k0 + 4) * 64 + col], W[(k0 + 5) * 64 + col]);
  v.w = pk2(W[(k0 + 6) * 64 + col], W[(k0 + 7) * 64 + col]);
  wfrag[idx] = v;
}

__global__ __launch_bounds__(512) void k_bscatter(
    const int* __restrict__ src1, const int* __restrict__ dst1, int E1,
    const int* __restrict__ src2, const int* __restrict__ dst2, int E2,
    int* __restrict__ ecur, unsigned* __restrict__ ebuf, int N, int nbuk) {
  __shared__ int cnt[512];
  __shared__ int gbase[512];
  int t = threadIdx.x;
  cnt[t] = 0;
  __syncthreads();
  int tile = blockIdx.x;
  int T1 = (E1 + TILE - 1) / TILE;
  const int* srcp; const int* dstp; int Elim, ofs, base;
  if (tile < T1) { srcp = src1; dstp = dst1; Elim = E1; ofs = 0; base = tile * TILE; }
  else { srcp = src2; dstp = dst2; Elim = E2; ofs = N; base = (tile - T1) * TILE; }
  unsigned pk[EPT];   // bucket(9) | rank<<9
  unsigned pv[EPT];   // dstLocal(10)<<19 | src(19)
  #pragma unroll
  for (int k = 0; k < EPT; ++k) {
    int e = base + k * 512 + t;
    if (e < Elim) {
      int d = dstp[e] + ofs;
      int b = d >> 10;
      int r = atomicAdd(&cnt[b], 1);
      pk[k] = (unsigned)b | ((unsigned)r << 9);
      pv[k] = ((unsigned)(d & 1023) << 19) | (unsigned)(srcp[e] + ofs);
    } else {
      pk[k] = 0xFFFFFFFFu;
    }
  }
  __syncthreads();
  if (t < nbuk && cnt[t] > 0) gbase[t] = atomicAdd(&ecur[t], cnt[t]);
  __syncthreads();
  #pragma unroll
  for (int k = 0; k < EPT; ++k) {
    if (pk[k] != 0xFFFFFFFFu) {
      int b = pk[k] & 511;
      int r = pk[k] >> 9;
      ebuf[gbase[b] + r] = pv[k];
    }
  }
}

__global__ __launch_bounds__(512) void k_bscan2(const int* __restrict__ ecur,
    int* __restrict__ ebase, int nbuk) {
  __shared__ int lds[512];
  int t = threadIdx.x;
  int s = (t < nbuk) ? (ecur[t] - t * CAP) : 0;
  lds[t] = s; __syncthreads();
  int acc = s;
  for (int o = 1; o < 512; o <<= 1) {
    int add = (t >= o) ? lds[t - o] : 0;
    __syncthreads();
    acc += add; lds[t] = acc;
    __syncthreads();
  }
  if (t < nbuk) ebase[t] = acc - s;
}

__global__ __launch_bounds__(256) void k_bcsr(const unsigned* __restrict__ ebuf,
    const int* __restrict__ ecur, const int* __restrict__ ebase,
    int* __restrict__ off, int* __restrict__ csr, int N2) {
  __shared__ int hist[1024];
  __shared__ int lofs[1024];
  __shared__ int sc[256];
  int b = blockIdx.x, t = threadIdx.x;
  int nb0 = b << 10;
  int bn = N2 - nb0; if (bn > 1024) bn = 1024;
  int s_beg = b * CAP, s_end = ecur[b];
  int base = ebase[b];
  #pragma unroll
  for (int k = 0; k < 4; ++k) hist[t * 4 + k] = 0;
  __syncthreads();
  for (int e = s_beg + t; e < s_end; e += 256) atomicAdd(&hist[ebuf[e] >> 19], 1);
  __syncthreads();
  int h0 = hist[t * 4 + 0], h1 = hist[t * 4 + 1], h2 = hist[t * 4 + 2], h3 = hist[t * 4 + 3];
  int s = h0 + h1 + h2 + h3;
  sc[t] = s; __syncthreads();
  int acc = s;
  for (int o = 1; o < 256; o <<= 1) {
    int add = (t >= o) ? sc[t - o] : 0;
    __syncthreads();
    acc += add; sc[t] = acc;
    __syncthreads();
  }
  int run = acc - s;
  lofs[t * 4 + 0] = run; run += h0;
  lofs[t * 4 + 1] = run; run += h1;
  lofs[t * 4 + 2] = run; run += h2;
  lofs[t * 4 + 3] = run;
  __syncthreads();
  #pragma unroll
  for (int k = 0; k < 4; ++k) {
    int j = t * 4 + k;
    if (j < bn) off[nb0 + j] = base + lofs[j];
  }
  __syncthreads();
  for (int e = s_beg + t; e < s_end; e += 256) {
    unsigned p = ebuf[e];
    int r = atomicAdd(&lofs[p >> 19], 1);
    csr[base + r] = (int)(p & 0x7FFFFu);
  }
}

// ---------------- GIN1 fused: gather x + Linear(6->64) + relu + MFMA Linear(64->64) ----------------
#define ACC6(u) { a0 += blo(u.x); a1 += bhi(u.x); a2 += blo(u.y); a3 += bhi(u.y); a4 += blo(u.z); a5 += bhi(u.z); }
__global__ __launch_bounds__(256) void k_gin1f(const uint4* __restrict__ xb4,
    const int* __restrict__ off, const int* __restrict__ csr,
    const float* __restrict__ W1, const float* __restrict__ b1,
    const uint4* __restrict__ wf2, const float* __restrict__ b2,
    ushort_t* __restrict__ hr, int n) {
  __shared__ __align__(16) ushort_t t1s[32][72];
  __shared__ float sh[4][8][FIN];
  int t = threadIdx.x, w = t >> 6, lane = t & 63;
  int nd = lane >> 3, sl = lane & 7;
  int blk = xcd_swz(blockIdx.x, gridDim.x);
  int nb0 = blk * 32;
  int i = nb0 + w * 8 + nd;

  float w1r[FIN];
  #pragma unroll
  for (int k = 0; k < FIN; ++k) w1r[k] = W1[k * 64 + lane];
  float bb1 = b1[lane];

  float a0 = 0, a1 = 0, a2 = 0, a3 = 0, a4 = 0, a5 = 0;
  if (i < n) {
    int e0 = off[i], e1 = off[i + 1];
    int e = e0 + sl;
    for (; e + 8 < e1; e += 16) {
      uint4 u = xb4[csr[e]];
      uint4 v = xb4[csr[e + 8]];
      ACC6(u); ACC6(v);
    }
    if (e < e1) { uint4 u = xb4[csr[e]]; ACC6(u); }
    if (sl == 0) { uint4 u = xb4[i]; ACC6(u); }
  }
  #pragma unroll
  for (int m = 1; m < 8; m <<= 1) {
    a0 += __shfl_xor(a0, m); a1 += __shfl_xor(a1, m); a2 += __shfl_xor(a2, m);
    a3 += __shfl_xor(a3, m); a4 += __shfl_xor(a4, m); a5 += __shfl_xor(a5, m);
  }
  if (sl < FIN) {
    float v = (sl == 0) ? a0 : (sl == 1) ? a1 : (sl == 2) ? a2 : (sl == 3) ? a3 : (sl == 4) ? a4 : a5;
    sh[w][nd][sl] = v;
  }
  #pragma unroll
  for (int nd2 = 0; nd2 < 8; ++nd2) {
    float h = bb1;
    #pragma unroll
    for (int k = 0; k < FIN; ++k) h = fmaf(sh[w][nd2][k], w1r[k], h);
    t1s[w * 8 + nd2][lane] = f2b(fmaxf(h, 0.f));
  }
  __syncthreads();
  if (w < 2) {
    int g = lane >> 4, c = lane & 15;
    bf16x8 af[4][2];
    #pragma unroll
    for (int mt = 0; mt < 4; ++mt)
      #pragma unroll
      for (int kh = 0; kh < 2; ++kh) af[mt][kh] = asfrag(wf2[(mt * 2 + kh) * 64 + lane]);
    int r0 = w * 16 + c;
    bf16x8 bf0 = asfrag(*(const uint4*)&t1s[r0][8 * g]);
    bf16x8 bf1 = asfrag(*(const uint4*)&t1s[r0][8 * g + 32]);
    f32x4 acc[4];
    #pragma unroll
    for (int mt = 0; mt < 4; ++mt) {
      acc[mt] = (f32x4){b2[mt * 16 + 4 * g + 0], b2[mt * 16 + 4 * g + 1],
                        b2[mt * 16 + 4 * g + 2], b2[mt * 16 + 4 * g + 3]};
      acc[mt] = __builtin_amdgcn_mfma_f32_16x16x32_bf16(af[mt][0], bf0, acc[mt], 0, 0, 0);
      acc[mt] = __builtin_amdgcn_mfma_f32_16x16x32_bf16(af[mt][1], bf1, acc[mt], 0, 0, 0);
    }
    #pragma unroll
    for (int mt = 0; mt < 4; ++mt) {
      uint2 pv;
      pv.x = pk2(acc[mt][0], acc[mt][1]);
      pv.y = pk2(acc[mt][2], acc[mt][3]);
      *(uint2*)&t1s[r0][mt * 16 + 4 * g] = pv;
    }
    int n2 = lane >> 2, ch = (lane & 3) * 16;
    uint4 s0 = *(const uint4*)&t1s[w * 16 + n2][ch];
    uint4 s1 = *(const uint4*)&t1s[w * 16 + n2][ch + 8];
    int orow = nb0 + w * 16 + n2;
    if (orow < n) {
      uint4* op = (uint4*)(hr + (size_t)orow * 64);
      op[(lane & 3) * 2] = s0;
      op[(lane & 3) * 2 + 1] = s1;
    }
  }
}

// ---------------- k_agg64: float2 packed accumulation + XCD swizzle ----------------
__device__ __forceinline__ float2 up2(unsigned v) { return make_float2(blo(v), bhi(v)); }
#define PACC(u) { float2 q0 = up2(u.x), q1 = up2(u.y), q2 = up2(u.z), q3 = up2(u.w); \
                  c0.x += q0.x; c0.y += q0.y; c1.x += q1.x; c1.y += q1.y; \
                  c2.x += q2.x; c2.y += q2.y; c3.x += q3.x; c3.y += q3.y; }
__global__ __launch_bounds__(256) void k_agg64(const ushort_t* __restrict__ hb,
    const int* __restrict__ off, const int* __restrict__ csr,
    ushort_t* __restrict__ aggb, int n) {
  int t = threadIdx.x, w = t >> 6, lane = t & 63;
  int blk = xcd_swz(blockIdx.x, gridDim.x);
  int i = blk * 4 + w;
  if (i >= n) return;
  int grp = lane >> 3, sl = lane & 7;
  int e0 = off[i], e1 = off[i + 1];
  const uint4* hb4 = (const uint4*)hb;
  float2 c0 = {0, 0}, c1 = {0, 0}, c2 = {0, 0}, c3 = {0, 0};
  int e = e0 + grp;
  for (; e + 8 < e1; e += 16) {
    int sa = csr[e], sb = csr[e + 8];
    uint4 ua = hb4[(size_t)sa * 8 + sl];
    uint4 ub = hb4[(size_t)sb * 8 + sl];
    PACC(ua); PACC(ub);
  }
  if (e < e1) {
    int sa = csr[e];
    uint4 ua = hb4[(size_t)sa * 8 + sl];
    PACC(ua);
  }
  #pragma unroll
  for (int m = 8; m < 64; m <<= 1) {
    c0.x += __shfl_xor(c0.x, m); c0.y += __shfl_xor(c0.y, m);
    c1.x += __shfl_xor(c1.x, m); c1.y += __shfl_xor(c1.y, m);
    c2.x += __shfl_xor(c2.x, m); c2.y += __shfl_xor(c2.y, m);
    c3.x += __shfl_xor(c3.x, m); c3.y += __shfl_xor(c3.y, m);
  }
  if (grp == 0) {
    uint4 us = hb4[(size_t)i * 8 + sl];
    PACC(us);
    uint4 o;
    o.x = pk2(c0.x, c0.y); o.y = pk2(c1.x, c1.y);
    o.z = pk2(c2.x, c2.y); o.w = pk2(c3.x, c3.y);
    ((uint4*)aggb)[(size_t)i * 8 + sl] = o;
  }
}

// ---------------- k_mlp2_mfma ----------------
__global__ __launch_bounds__(256) void k_mlp2_mfma(const ushort_t* __restrict__ aggb,
    const uint4* __restrict__ wf3, const float* __restrict__ b3,
    const uint4* __restrict__ wf4, const float* __restrict__ b4,
    ushort_t* __restrict__ zb, int n) {
  __shared__ __align__(16) ushort_t lds[4][16][72];
  int t = threadIdx.x, w = t >> 6, l = t & 63;
  int g = l >> 4, c = l & 15;
  bf16x8 a3[4][2], a4[4][2];
  #pragma unroll
  for (int mt = 0; mt < 4; ++mt)
    #pragma unroll
    for (int kh = 0; kh < 2; ++kh) {
      a3[mt][kh] = asfrag(wf3[(mt * 2 + kh) * 64 + l]);
      a4[mt][kh] = asfrag(wf4[(mt * 2 + kh) * 64 + l]);
    }
  float bs3[4][4], bs4[4][4];
  #pragma unroll
  for (int mt = 0; mt < 4; ++mt)
    #pragma unroll
    for (int r = 0; r < 4; ++r) {
      bs3[mt][r] = b3[mt * 16 + 4 * g + r];
      bs4[mt][r] = b4[mt * 16 + 4 * g + r];
    }
  int ntile = (n + 15) >> 4;
  for (int tau = blockIdx.x * 4 + w; tau < ntile; tau += gridDim.x * 4) {
    int nb = tau << 4;
    int row = nb + c; if (row >= n) row = n - 1;
    const uint4* rp = (const uint4*)(aggb + (size_t)row * 64);
    bf16x8 bf0 = asfrag(rp[g]);
    bf16x8 bf1 = asfrag(rp[g + 4]);
    f32x4 acc[4];
    #pragma unroll
    for (int mt = 0; mt < 4; ++mt) {
      acc[mt] = (f32x4){bs3[mt][0], bs3[mt][1], bs3[mt][2], bs3[mt][3]};
      acc[mt] = __builtin_amdgcn_mfma_f32_16x16x32_bf16(a3[mt][0], bf0, acc[mt], 0, 0, 0);
      acc[mt] = __builtin_amdgcn_mfma_f32_16x16x32_bf16(a3[mt][1], bf1, acc[mt], 0, 0, 0);
    }
    #pragma unroll
    for (int mt = 0; mt < 4; ++mt) {
      uint2 pv;
      pv.x = pk2(fmaxf(acc[mt][0], 0.f), fmaxf(acc[mt][1], 0.f));
      pv.y = pk2(fmaxf(acc[mt][2], 0.f), fmaxf(acc[mt][3], 0.f));
      *(uint2*)&lds[w][c][mt * 16 + 4 * g] = pv;
    }
    bf16x8 h0 = asfrag(*(const uint4*)&lds[w][c][8 * g]);
    bf16x8 h1 = asfrag(*(const uint4*)&lds[w][c][8 * g + 32]);
    f32x4 ac2[4];
    #pragma unroll
    for (int mt = 0; mt < 4; ++mt) {
      ac2[mt] = (f32x4){bs4[mt][0], bs4[mt][1], bs4[mt][2], bs4[mt][3]};
      ac2[mt] = __builtin_amdgcn_mfma_f32_16x16x32_bf16(a4[mt][0], h0, ac2[mt], 0, 0, 0);
      ac2[mt] = __builtin_amdgcn_mfma_f32_16x16x32_bf16(a4[mt][1], h1, ac2[mt], 0, 0, 0);
    }
    #pragma unroll
    for (int mt = 0; mt < 4; ++mt) {
      uint2 pv;
      pv.x = pk2(ac2[mt][0], ac2[mt][1]);
      pv.y = pk2(ac2[mt][2], ac2[mt][3]);
      *(uint2*)&lds[w][c][mt * 16 + 4 * g] = pv;
    }
    int n2 = l >> 2, ch = (l & 3) * 16;
    uint4 s0 = *(const uint4*)&lds[w][n2][ch];
    uint4 s1 = *(const uint4*)&lds[w][n2][ch + 8];
    int orow = nb + n2;
    if (orow < n) {
      uint4* op = (uint4*)(zb + (size_t)orow * 64);
      op[(l & 3) * 2] = s0;
      op[(l & 3) * 2 + 1] = s1;
    }
  }
}

// ---------------- LN1 fused: stats + apply + relu (block per graph, in-place) ----------------
__global__ __launch_bounds__(256) void k_ln1(ushort_t* __restrict__ hr,
    const int* __restrict__ gstart, const float* __restrict__ w, const float* __restrict__ bb) {
  __shared__ uint4 st[LNCAP * 8];
  __shared__ float l1[256], l2[256];
  __shared__ float mm[2];
  int g = blockIdx.x, t = threadIdx.x;
  int s0 = gstart[g], s1 = gstart[g + 1], cnt = s1 - s0;
  uint4* src = (uint4*)hr + (size_t)s0 * 8;
  int nch = cnt * 8;
  bool fit = cnt <= LNCAP;
  float s = 0.f, ss = 0.f;
  for (int j = t; j < nch; j += 256) {
    uint4 u = src[j];
    if (fit) st[j] = u;
    float v0 = blo(u.x), v1 = bhi(u.x), v2 = blo(u.y), v3 = bhi(u.y);
    float v4 = blo(u.z), v5 = bhi(u.z), v6 = blo(u.w), v7 = bhi(u.w);
    s += ((v0 + v1) + (v2 + v3)) + ((v4 + v5) + (v6 + v7));
    ss += ((v0 * v0 + v1 * v1) + (v2 * v2 + v3 * v3)) + ((v4 * v4 + v5 * v5) + (v6 * v6 + v7 * v7));
  }
  l1[t] = s; l2[t] = ss;
  __syncthreads();
  for (int o = 128; o > 0; o >>= 1) {
    if (t < o) { l1[t] += l1[t + o]; l2[t] += l2[t + o]; }
    __syncthreads();
  }
  if (t == 0) {
    float cf = (float)cnt;
    float norm = fmaxf(cf, 1.f) * 64.f;
    float mean = l1[0] / norm;
    float var = fmaxf(l2[0] / norm - mean * mean, 0.f);
    mm[0] = mean; mm[1] = rsqrtf(var + 1e-5f);
  }
  __syncthreads();
  float mean = mm[0], inv = mm[1];
  for (int j = t; j < nch; j += 256) {
    uint4 u = fit ? st[j] : src[j];
    int q = j & 7;
    float4 w0 = *(const float4*)(w + q * 8);
    float4 w1 = *(const float4*)(w + q * 8 + 4);
    float4 c0 = *(const float4*)(bb + q * 8);
    float4 c1 = *(const float4*)(bb + q * 8 + 4);
    uint4 o;
    o.x = pk2(fmaxf((blo(u.x) - mean) * inv * w0.x + c0.x, 0.f),
              fmaxf((bhi(u.x) - mean) * inv * w0.y + c0.y, 0.f));
    o.y = pk2(fmaxf((blo(u.y) - mean) * inv * w0.z + c0.z, 0.f),
              fmaxf((bhi(u.y) - mean) * inv * w0.w + c0.w, 0.f));
    o.z = pk2(fmaxf((blo(u.z) - mean) * inv * w1.x + c1.x, 0.f),
              fmaxf((bhi(u.z) - mean) * inv * w1.y + c1.y, 0.f));
    o.w = pk2(fmaxf((blo(u.w) - mean) * inv * w1.z + c1.z, 0.f),
              fmaxf((bhi(u.w) - mean) * inv * w1.w + c1.w, 0.f));
    src[j] = o;
  }
}

// ---------------- LN2 + pool fused ----------------
__global__ __launch_bounds__(256) void k_ln2pool(const ushort_t* __restrict__ zb,
    const int* __restrict__ gstart, const float* __restrict__ w, const float* __restrict__ bb,
    float* __restrict__ emb) {
  __shared__ unsigned st[LNCAP * 32];
  __shared__ float l1[256], l2[256];
  __shared__ float mm[2];
  int g = blockIdx.x, t = threadIdx.x;
  int s0 = gstart[g], s1 = gstart[g + 1], cnt = s1 - s0;
  const unsigned* src = (const unsigned*)zb + (size_t)s0 * 32;
  int nu = cnt * 32;
  bool fit = cnt <= LNCAP;
  float s = 0.f, ss = 0.f;
  for (int j = t; j < nu; j += 256) {
    unsigned u = src[j];
    if (fit) st[j] = u;
    float v0 = blo(u), v1 = bhi(u);
    s += v0 + v1;
    ss += v0 * v0 + v1 * v1;
  }
  l1[t] = s; l2[t] = ss;
  __syncthreads();
  for (int o = 128; o > 0; o >>= 1) {
    if (t < o) { l1[t] += l1[t + o]; l2[t] += l2[t + o]; }
    __syncthreads();
  }
  if (t == 0) {
    float cf = (float)cnt;
    float norm = fmaxf(cf, 1.f) * 64.f;
    float mean = l1[0] / norm;
    float var = fmaxf(l2[0] / norm - mean * mean, 0.f);
    mm[0] = mean; mm[1] = rsqrtf(var + 1e-5f);
  }
  __syncthreads();
  float mean = mm[0], inv = mm[1];
  int c2 = t & 31, sub = t >> 5;
  float w0 = w[c2 * 2], w1 = w[c2 * 2 + 1], b0 = bb[c2 * 2], b1v = bb[c2 * 2 + 1];
  float acc0 = 0.f, acc1 = 0.f;
  for (int i = sub; i < cnt; i += 8) {
    unsigned u = fit ? st[i * 32 + c2] : src[(size_t)i * 32 + c2];
    acc0 += fmaxf((blo(u) - mean) * inv * w0 + b0, 0.f);
    acc1 += fmaxf((bhi(u) - mean) * inv * w1 + b1v, 0.f);
  }
  __syncthreads();
  l1[t] = acc0; l2[t] = acc1;
  __syncthreads();
  if (sub == 0) {
    float t0 = 0.f, t1v = 0.f;
    #pragma unroll
    for (int sx = 0; sx < 8; ++sx) { t0 += l1[sx * 32 + c2]; t1v += l2[sx * 32 + c2]; }
    float cf = fmaxf((float)cnt, 1.f);
    emb[g * 64 + c2 * 2]     = t0 + t0 / cf;
    emb[g * 64 + c2 * 2 + 1] = t1v + t1v / cf;
  }
}

// ---------------- head MLP ----------------
__global__ __launch_bounds__(128) void k_head(const float* __restrict__ emb1,
    const float* __restrict__ emb2, const float* __restrict__ d1, const float* __restrict__ d2,
    const float* __restrict__ Wf1, const float* __restrict__ bf1,
    const float* __restrict__ Wf2, const float* __restrict__ bf2,
    const float* __restrict__ Wo, const float* __restrict__ bo, float* __restrict__ out) {
  int g = blockIdx.x, t = threadIdx.x;
  __shared__ float v[138], h1s[128], h2s[64];
  if (t < 64) v[t] = emb1[g * 64 + t];
  else v[t] = emb2[g * 64 + (t - 64)];
  if (t < 5) v[128 + t] = d1[g * 5 + t];
  else if (t < 10) v[133 + (t - 5)] = d2[g * 5 + (t - 5)];
  __syncthreads();
  float a = bf1[t];
  for (int k = 0; k < 138; ++k) a = fmaf(v[k], Wf1[k * 128 + t], a);
  h1s[t] = fmaxf(a, 0.f);
  __syncthreads();
  if (t < 64) {
    float a2 = bf2[t];
    #pragma unroll 8
    for (int k = 0; k < 128; ++k) a2 = fmaf(h1s[k], Wf2[k * 64 + t], a2);
    h2s[t] = fmaxf(a2, 0.f);
  }
  __syncthreads();
  if (t == 0) {
    float s = bo[0];
    for (int k = 0; k < 64; ++k) s += h2s[k] * Wo[k];
    out[g] = s;
  }
}

extern "C" void kernel_launch(void* const* d_in, const int* in_sizes, int n_in,
                              void* d_out, int out_size, void* d_ws, size_t ws_size,
                              hipStream_t stream) {
  const float* x1     = (const float*)d_in[0];
  const int*   ei1    = (const int*)d_in[1];
  const int*   batch1 = (const int*)d_in[2];
  const float* x2     = (const float*)d_in[3];
  const int*   ei2    = (const int*)d_in[4];
  const int*   batch2 = (const int*)d_in[5];
  const float* d1     = (const float*)d_in[6];
  const float* d2     = (const float*)d_in[7];
  const float* W1  = (const float*)d_in[8],  *b1  = (const float*)d_in[9];
  const float* W2  = (const float*)d_in[10], *b2  = (const float*)d_in[11];
  const float* ln1w = (const float*)d_in[12], *ln1b = (const float*)d_in[13];
  const float* W3  = (const float*)d_in[14], *b3  = (const float*)d_in[15];
  const float* W4  = (const float*)d_in[16], *b4  = (const float*)d_in[17];
  const float* ln2w = (const float*)d_in[18], *ln2b = (const float*)d_in[19];
  const float* Wf1 = (const float*)d_in[20], *bf1 = (const float*)d_in[21];
  const float* Wf2 = (const float*)d_in[22], *bf2 = (const float*)d_in[23];
  const float* Wo  = (const float*)d_in[24], *bo  = (const float*)d_in[25];
  float* out = (float*)d_out;

  const int N = in_sizes[0] / FIN;
  const int G = in_sizes[6] / 5;
  const int E1 = in_sizes[1] / 2;
  const int E2 = in_sizes[4] / 2;
  const int N2 = 2 * N;
  const int Etot = E1 + E2;
  const int NBUK = (N2 + 1023) >> 10;   // <= 512 (requires 2N <= 524288)

  char* p = (char*)d_ws;
  auto alloc = [&](size_t bytes) { void* r = p; p += (bytes + 255) & ~(size_t)255; return r; };
  int*      off    = (int*)alloc((size_t)(N2 + 1) * 4);
  int*      ecur   = (int*)alloc(512 * 4);
  int*      ebase  = (int*)alloc(513 * 4);
  int*      csr    = (int*)alloc((size_t)Etot * 4);
  int*      gstart = (int*)alloc((size_t)(2 * G + 1) * 4);
  uint4*    wfrag  = (uint4*)alloc(3 * 512 * 16);
  ushort_t* bufA   = (ushort_t*)alloc((size_t)N2 * 64 * 2);  // hr -> (in-place LN) -> zb
  ushort_t* bufB   = (ushort_t*)alloc((size_t)N2 * 64 * 2);  // xb+ebuf -> aggb
  float*    emb    = (float*)alloc((size_t)2 * G * 64 * 4);

  unsigned* xb   = (unsigned*)bufB;
  unsigned* ebuf = (unsigned*)((char*)bufB + (size_t)N2 * 16);
  ushort_t* hr   = bufA;
  ushort_t* aggb = bufB;
  ushort_t* zb   = bufA;

  const uint4* wf2 = wfrag;
  const uint4* wf3 = wfrag + 512;
  const uint4* wf4 = wfrag + 1024;

  const int SCAT   = (E1 + TILE - 1) / TILE + (E2 + TILE - 1) / TILE;
  const int GRID_F = (((N2 + 31) / 32) + 7) & ~7;   // multiple of 8 for xcd swizzle
  const int GRID_W = (((N2 + 3) / 4) + 7) & ~7;     // multiple of 8 for xcd swizzle
  const int GRID_P = (N2 * 4 + 255) / 256;

  k_wpack<<<7 + GRID_P, 256, 0, stream>>>(W2, W3, W4, wfrag, ecur, off, NBUK, N2, Etot,
                                          x1, x2, batch1, batch2, xb, gstart, N, G);
  k_bscatter<<<SCAT, 512, 0, stream>>>(ei1, ei1 + E1, E1, ei2, ei2 + E2, E2, ecur, ebuf, N, NBUK);
  k_bscan2<<<1, 512, 0, stream>>>(ecur, ebase, NBUK);
  k_bcsr<<<NBUK, 256, 0, stream>>>(ebuf, ecur, ebase, off, csr, N2);

  k_gin1f<<<GRID_F, 256, 0, stream>>>((const uint4*)xb, off, csr, W1, b1, wf2, b2, hr, N2);
  k_ln1<<<2 * G, 256, 0, stream>>>(hr, gstart, ln1w, ln1b);
  k_agg64<<<GRID_W, 256, 0, stream>>>(hr, off, csr, aggb, N2);
  k_mlp2_mfma<<<2048, 256, 0, stream>>>(aggb, wf3, b3, wf4, b4, zb, N2);
  k_ln2pool<<<2 * G, 256, 0, stream>>>(zb, gstart, ln2w, ln2b, emb);

  k_head<<<G, 128, 0, stream>>>(emb, emb + (size_t)G * 64, d1, d2, Wf1, bf1, Wf2, bf2, Wo, bo, out);
}